// Round 7
// baseline (262.987 us; speedup 1.0000x reference)
//
#include <hip/hip_runtime.h>

#define MDIM 8192
#define NDIM 8192
#define KDIM 64

typedef __attribute__((ext_vector_type(8))) short bf16x8;
typedef __attribute__((ext_vector_type(4))) float f32x4;

__device__ __forceinline__ unsigned short f32_to_bf16(float f) {
    union { float f; unsigned int u; } v;
    v.f = f;
    unsigned int u = v.u;
    u += 0x7FFFu + ((u >> 16) & 1u);  // round-to-nearest-even
    return (unsigned short)(u >> 16);
}

// ---------------------------------------------------------------------------
// 64x256 tile. Rationale (R7): the only lever that ever moved this kernel is
// store-segment contiguity (64->256 B = -28 us). A 128-wide tile caps each
// C-row at 512 B; 256-wide gives 1 KB per row, and the epilogue emits ONE
// full row per store instruction (1 KB contiguous) -- instruction-identical
// to the 6.4 TB/s fill kernel's stream. LDS: 40 KB XOR-swizzled staging
// (R2-proven layout, no pad) -> 4 blocks/CU.
//
// LDS layout (ushort units), granule = 8 ushorts = 16 B:
//   sA [64 rows][64 k]:  elem (r,k) at r*64 + ((k>>3) ^ (r&7))*8 + (k&7)
//   sB [256 n ][64 k]:  elem (n,k) at n*64 + ((k>>3) ^ (n&7))*8 + (k&7)
// Fragment ds_read_b128 at granule (ks*4+quad) ^ (row&7): 16 rows x same
// granule -> bank classes spread by XOR -> balanced (8 words/bank = the b128
// minimum).
// ---------------------------------------------------------------------------
__global__ __launch_bounds__(256, 4)
void tmatmul_kernel(const float* __restrict__ A, const float* __restrict__ B,
                    float* __restrict__ C) {
    __shared__ __align__(16) unsigned short smem[20480];  // 40 KB
    unsigned short* sA = smem;         // 8 KB
    unsigned short* sB = smem + 4096;  // 32 KB

    const int tid = threadIdx.x;
    const int m0 = blockIdx.y << 6;  // 64-row band
    const int n0 = blockIdx.x << 8;  // 256-col band

    // ---- Stage A: 64x64 fp32 = 16 KB, fully linear float4 reads. ----
#pragma unroll
    for (int i = 0; i < 4; ++i) {
        const int f = (i << 10) + (tid << 2);  // float index within tile (linear)
        const int row = f >> 6;
        const int col = f & 63;
        const float4 v =
            *reinterpret_cast<const float4*>(&A[(size_t)m0 * KDIM + f]);
        ushort4 h;
        h.x = f32_to_bf16(v.x);
        h.y = f32_to_bf16(v.y);
        h.z = f32_to_bf16(v.z);
        h.w = f32_to_bf16(v.w);
        *reinterpret_cast<ushort4*>(
            &sA[row * 64 + (((col >> 3) ^ (row & 7)) << 3) + (col & 7)]) = h;
    }

    // ---- Stage B: 64x256 fp32, transposed into sB[n][k]. Reads coalesced
    //      along n (1 KB per wave-read); 8 B swizzled LDS writes. ----
    {
        const int n = tid;  // 0..255
#pragma unroll
        for (int i = 0; i < 16; ++i) {
            const int k0 = i << 2;  // 0,4,...,60
            const size_t gb = (size_t)k0 * NDIM + n0 + n;
            ushort4 h;
            h.x = f32_to_bf16(B[gb]);
            h.y = f32_to_bf16(B[gb + NDIM]);
            h.z = f32_to_bf16(B[gb + 2 * NDIM]);
            h.w = f32_to_bf16(B[gb + 3 * NDIM]);
            *reinterpret_cast<ushort4*>(
                &sB[n * 64 + (((k0 >> 3) ^ (n & 7)) << 3) + (k0 & 7)]) = h;
        }
    }

    __syncthreads();

    // ---- Compute: 4 waves side-by-side in n. Wave wv owns 64 rows x cols
    //      [wv*64, +64): 4 mt x 4 nt MFMA tiles, K=64 = 2 steps. ----
    const int lane = tid & 63;
    const int wv = tid >> 6;
    const int wn = wv << 6;
    const int l15 = lane & 15;
    const int quad = lane >> 4;
    const int x = l15 & 7;  // row-dependent XOR key
    const char* sAb = (const char*)sA;
    const char* sBb = (const char*)sB;

    bf16x8 afrag[4][2];
#pragma unroll
    for (int mt = 0; mt < 4; ++mt)
#pragma unroll
        for (int ks = 0; ks < 2; ++ks)
            afrag[mt][ks] = *reinterpret_cast<const bf16x8*>(
                sAb + (mt * 16 + l15) * 128 + (((ks * 4 + quad) ^ x) << 4));

    f32x4 acc[4][4];
    const f32x4 zero = {0.0f, 0.0f, 0.0f, 0.0f};
#pragma unroll
    for (int mt = 0; mt < 4; ++mt)
#pragma unroll
        for (int nt = 0; nt < 4; ++nt)
            acc[mt][nt] = zero;

    // Operand swap: D = (B^T-frag) x (A^T-frag) = C^T tile. Lane holds
    // C[m = mt*16 + l15][n = wn + nt*16 + quad*4 + reg].
#pragma unroll
    for (int nt = 0; nt < 4; ++nt) {
        const char* rb = sBb + (wn + nt * 16 + l15) * 128;
        const bf16x8 bf0 = *reinterpret_cast<const bf16x8*>(rb + ((quad ^ x) << 4));
        const bf16x8 bf1 =
            *reinterpret_cast<const bf16x8*>(rb + (((4 + quad) ^ x) << 4));
#pragma unroll
        for (int mt = 0; mt < 4; ++mt) {
            acc[mt][nt] = __builtin_amdgcn_mfma_f32_16x16x32_bf16(
                bf0, afrag[mt][0], acc[mt][nt], 0, 0, 0);
            acc[mt][nt] = __builtin_amdgcn_mfma_f32_16x16x32_bf16(
                bf1, afrag[mt][1], acc[mt][nt], 0, 0, 0);
        }
    }

    // All waves done reading sA/sB before LDS is recycled as the bounce.
    __syncthreads();

    // ---- Epilogue: two half-passes through a 32-row x 256-col bounce (32 KB).
    //      Scatter: row r (=local row & 31), granule g = wv*16 + nt*4 + quad
    //      stored at g ^ (r&7) -> bank-balanced. Gather: one FULL row per
    //      store instruction -> 1 KB contiguous plain stores. ----
    float* bounce = reinterpret_cast<float*>(smem);
#pragma unroll
    for (int p = 0; p < 2; ++p) {
#pragma unroll
        for (int h = 0; h < 2; ++h) {
            const int mt = (p << 1) + h;       // acc row-tile for this pass
            const int r = (h << 4) + l15;      // bounce row 0..31
#pragma unroll
            for (int nt = 0; nt < 4; ++nt) {
                const int g = (wv << 4) + (nt << 2) + quad;  // 0..63
                *reinterpret_cast<f32x4*>(
                    &bounce[(r << 8) + ((g ^ (r & 7)) << 2)]) = acc[mt][nt];
            }
        }
        __syncthreads();
        // Wave wv streams rows [wv*8, +8): one 1 KB store per row.
#pragma unroll
        for (int j = 0; j < 8; ++j) {
            const int r = (wv << 3) + j;
            const f32x4 v = *reinterpret_cast<const f32x4*>(
                &bounce[(r << 8) + ((lane ^ (r & 7)) << 2)]);
            *reinterpret_cast<f32x4*>(
                &C[(size_t)(m0 + (p << 5) + r) * NDIM + n0 + (lane << 2)]) = v;
        }
        if (p == 0) __syncthreads();  // reads done before pass-1 scatter
    }
}

extern "C" void kernel_launch(void* const* d_in, const int* in_sizes, int n_in,
                              void* d_out, int out_size, void* d_ws, size_t ws_size,
                              hipStream_t stream) {
    const float* A = (const float*)d_in[0];
    const float* B = (const float*)d_in[1];
    float* C = (float*)d_out;
    dim3 grid(NDIM / 256, MDIM / 64);  // (32, 128)
    tmatmul_kernel<<<grid, dim3(256, 1, 1), 0, stream>>>(A, B, C);
}

// Round 8
// 262.796 us; speedup vs baseline: 1.0007x; 1.0007x over previous
//
#include <hip/hip_runtime.h>

#define MDIM 8192
#define NDIM 8192
#define KDIM 64

typedef __attribute__((ext_vector_type(8))) short bf16x8;
typedef __attribute__((ext_vector_type(4))) float f32x4;

__device__ __forceinline__ unsigned short f32_to_bf16(float f) {
    union { float f; unsigned int u; } v;
    v.f = f;
    unsigned int u = v.u;
    u += 0x7FFFu + ((u >> 16) & 1u);  // round-to-nearest-even
    return (unsigned short)(u >> 16);
}

// ---------------------------------------------------------------------------
// R8: 2-tile pipelined block. Each block computes two n-adjacent PROVEN
// 128x128 tiles (128 rows x 256 cols total). Rationale: stream-shape levers
// are exhausted (R1..R7); the untested axis is block-lifetime structure --
// per-block endpgm store-drain (4096 of them), A re-staging, and zero
// store/compute overlap. This halves block count, amortizes A, and overlaps
// tile0's store drain with tile1's MFMA. Layouts byte-identical to proven
// code (R2/R7 swizzled staging; R6 bounce epilogue).
//
// LDS (48 KB): sA [0,16K) | sB0 [16K,32K) | sB1 [32K,48K), all XOR-swizzled:
//   elem (r,k) ushort at r*64 + ((k>>3) ^ (r&7))*8 + (k&7)
// Epilogue slabs (4 KB/wave) recycle sB0 (tile0) and sB1 (tile1) post-compute.
// ---------------------------------------------------------------------------
__global__ __launch_bounds__(256, 3)
void tmatmul_kernel(const float* __restrict__ A, const float* __restrict__ B,
                    float* __restrict__ C) {
    __shared__ __align__(16) unsigned short smem[24576];  // 48 KB
    unsigned short* sA = smem;          // 16 KB
    unsigned short* sB0 = smem + 8192;  // 16 KB
    unsigned short* sB1 = smem + 16384; // 16 KB

    const int tid = threadIdx.x;
    const int m0 = blockIdx.y << 7;  // 128-row band
    const int n0 = blockIdx.x << 8;  // 256-col pair band

    // ---- Stage A: 128x64 fp32, fully linear float4 reads, swizzled write. ----
#pragma unroll
    for (int i = 0; i < 8; ++i) {
        const int f = (i << 10) + (tid << 2);  // linear float idx in tile
        const int row = f >> 6;
        const int col = f & 63;
        const float4 v = *reinterpret_cast<const float4*>(&A[(size_t)m0 * KDIM + f]);
        ushort4 h;
        h.x = f32_to_bf16(v.x);
        h.y = f32_to_bf16(v.y);
        h.z = f32_to_bf16(v.z);
        h.w = f32_to_bf16(v.w);
        *reinterpret_cast<ushort4*>(
            &sA[row * 64 + (((col >> 3) ^ (row & 7)) << 3) + (col & 7)]) = h;
    }

    // ---- B staging (R6 access pattern, swizzled write). ----
    auto stageB = [&](unsigned short* sB, int nt0) {
#pragma unroll
        for (int i = 0; i < 8; ++i) {
            const int n = (tid & 63) + ((i & 1) << 6);           // 0..127
            const int k0 = ((tid >> 6) << 2) + ((i >> 1) << 4);  // 0,4,...,60
            const size_t gb = (size_t)k0 * NDIM + nt0 + n;
            ushort4 h;
            h.x = f32_to_bf16(B[gb]);
            h.y = f32_to_bf16(B[gb + NDIM]);
            h.z = f32_to_bf16(B[gb + 2 * NDIM]);
            h.w = f32_to_bf16(B[gb + 3 * NDIM]);
            *reinterpret_cast<ushort4*>(
                &sB[n * 64 + (((k0 >> 3) ^ (n & 7)) << 3) + (k0 & 7)]) = h;
        }
    };

    stageB(sB0, n0);
    __syncthreads();  // b1: sA, sB0 ready

    // ---- Wave geometry (R6 2x2) + A fragments (loaded ONCE, reused). ----
    const int lane = tid & 63;
    const int wv = tid >> 6;
    const int wm = (wv >> 1) << 6;
    const int wn = (wv & 1) << 6;
    const int l15 = lane & 15;
    const int quad = lane >> 4;
    const int x = l15 & 7;  // row-dependent XOR key

    bf16x8 afrag[4][2];
#pragma unroll
    for (int mt = 0; mt < 4; ++mt)
#pragma unroll
        for (int ks = 0; ks < 2; ++ks)
            afrag[mt][ks] = *reinterpret_cast<const bf16x8*>(
                (const char*)sA + (wm + mt * 16 + l15) * 128 +
                (((ks * 4 + quad) ^ x) << 4));

    f32x4 acc[4][4];
    const f32x4 zero = {0.0f, 0.0f, 0.0f, 0.0f};

    // Operand-swapped MFMA block (proven): lane holds C[m=l15][n=quad*4+reg].
    auto compute = [&](const unsigned short* sB) {
#pragma unroll
        for (int mt = 0; mt < 4; ++mt)
#pragma unroll
            for (int nt = 0; nt < 4; ++nt)
                acc[mt][nt] = zero;
#pragma unroll
        for (int nt = 0; nt < 4; ++nt) {
            const char* rb = (const char*)sB + (wn + nt * 16 + l15) * 128;
            const bf16x8 bf0 =
                *reinterpret_cast<const bf16x8*>(rb + ((quad ^ x) << 4));
            const bf16x8 bf1 =
                *reinterpret_cast<const bf16x8*>(rb + (((4 + quad) ^ x) << 4));
#pragma unroll
            for (int mt = 0; mt < 4; ++mt) {
                acc[mt][nt] = __builtin_amdgcn_mfma_f32_16x16x32_bf16(
                    bf0, afrag[mt][0], acc[mt][nt], 0, 0, 0);
                acc[mt][nt] = __builtin_amdgcn_mfma_f32_16x16x32_bf16(
                    bf1, afrag[mt][1], acc[mt][nt], 0, 0, 0);
            }
        }
    };

    // R6's proven bounce epilogue; single 4 KB per-wave slab (LDS FIFO makes
    // the write-after-read across mt iterations safe without ping-pong).
    auto epilogue = [&](float* buf, int nt0) {
#pragma unroll
        for (int mt = 0; mt < 4; ++mt) {
#pragma unroll
            for (int nt = 0; nt < 4; ++nt) {
                const int g = (nt << 2) + quad;
                *reinterpret_cast<f32x4*>(&buf[(l15 << 6) + ((g ^ l15) << 2)]) =
                    acc[mt][nt];
            }
            const int m_base = m0 + wm + (mt << 4);
            const int n_base = nt0 + wn + (l15 << 2);
#pragma unroll
            for (int j = 0; j < 4; ++j) {
                const int rr = (j << 2) + quad;
                const f32x4 v = *reinterpret_cast<const f32x4*>(
                    &buf[(rr << 6) + ((l15 ^ rr) << 2)]);
                *reinterpret_cast<f32x4*>(
                    &C[(size_t)(m_base + rr) * NDIM + n_base]) = v;
            }
        }
    };

    // ---- Tile 0 compute, then prefetch-stage B1 (disjoint LDS, no race). ----
    compute(sB0);
    stageB(sB1, n0 + 128);
    __syncthreads();  // b2: all compute0 reads done (sB0 free), sB1 ready

    // ---- Store tile0; its drain overlaps tile1's MFMA below. ----
    epilogue(reinterpret_cast<float*>((char*)smem + 16384 + (wv << 12)), n0);

    // ---- Tile 1 compute (reuses afrag; overwrites acc after epilogue0 reads).
    compute(sB1);
    __syncthreads();  // b3: all compute1 reads done (sB1 free for slabs)

    // ---- Store tile1; single endpgm drain per 2 tiles. ----
    epilogue(reinterpret_cast<float*>((char*)smem + 32768 + (wv << 12)), n0 + 128);
}

extern "C" void kernel_launch(void* const* d_in, const int* in_sizes, int n_in,
                              void* d_out, int out_size, void* d_ws, size_t ws_size,
                              hipStream_t stream) {
    const float* A = (const float*)d_in[0];
    const float* B = (const float*)d_in[1];
    float* C = (float*)d_out;
    dim3 grid(NDIM / 256, MDIM / 128);  // (32, 64) = 2048 blocks
    tmatmul_kernel<<<grid, dim3(256, 1, 1), 0, stream>>>(A, B, C);
}